// Round 1
// 81.796 us; speedup vs baseline: 1.0787x; 1.0787x over previous
//
#include <hip/hip_runtime.h>

// 3-qubit, 2-layer RY/CNOT circuit -> <Z_i> per batch element.
// Algebraic folding:
//   - layer-0 RY(w[0,i]) composes with encoding RY(x_i*pi) (same wire, no CNOT
//     in between): half-angle t_i = x_i*(pi/2) + w[0,i]/2 -> ONE sincos/wire.
//   - layer-0 CNOT(0,1),CNOT(1,2) folded into the product-state build as the
//     index permutation [0,1,3,2,6,7,5,4] (register renames, zero cost).
//   - layer-1 CNOTs folded into the measurement index map (zero cost).
// Only real rotation work left: layer-1 RY on 3 wires = 12 pair rotations.
// 2 rows/thread; reads are stride-1 float4; output staged in LDS, stored as
// 3 coalesced float2 per thread. No __sincosf-with-pointer (scratch risk).

__global__ __launch_bounds__(256) void qfl_kernel(
    const float4* __restrict__ x, const float* __restrict__ w,
    float* __restrict__ out, int n)
{
    __shared__ float sout[1536];               // 512 rows x 3 outputs
    const int tid = threadIdx.x;
    const long long base = (long long)blockIdx.x * 512;

    // Wave-uniform weight trig (scalar loads; layer-0 halves fold into angles).
    const float hw0 = 0.5f * w[0], hw1 = 0.5f * w[1], hw2 = 0.5f * w[2];
    const float c3 = __cosf(0.5f * w[3]), s3 = __sinf(0.5f * w[3]);
    const float c4 = __cosf(0.5f * w[4]), s4 = __sinf(0.5f * w[4]);
    const float c5 = __cosf(0.5f * w[5]), s5 = __sinf(0.5f * w[5]);

    const float HPI = 0.5f * 3.14159f;         // matches reference PI literal

    #pragma unroll
    for (int half = 0; half < 2; ++half) {
        const long long e = base + half * 256 + tid;
        float4 xv = (e < (long long)n) ? x[e] : make_float4(0.f, 0.f, 0.f, 0.f);

        // composed half-angles: encoding + layer-0 RY
        float ta = fmaf(xv.x, HPI, hw0);
        float tb = fmaf(xv.y, HPI, hw1);
        float tc = fmaf(xv.z, HPI, hw2);
        float a0 = __cosf(ta), a1 = __sinf(ta);
        float b0 = __cosf(tb), b1 = __sinf(tb);
        float c0 = __cosf(tc), c1 = __sinf(tc);

        // product state with layer-0 CNOT(0,1),CNOT(1,2) pre-applied:
        // v[i] = raw[perm[i]], perm = [0,1,3,2,6,7,5,4]
        float a0b0 = a0 * b0, a0b1 = a0 * b1, a1b0 = a1 * b0, a1b1 = a1 * b1;
        float v0 = a0b0 * c0, v1 = a0b0 * c1;
        float v2 = a0b1 * c1, v3 = a0b1 * c0;
        float v4 = a1b1 * c0, v5 = a1b1 * c1;
        float v6 = a1b0 * c1, v7 = a1b0 * c0;

        // layer-1 RY wire0: pairs (k, k+4)
        { float u, v;
          u = v0; v = v4; v0 = c3*u - s3*v; v4 = s3*u + c3*v;
          u = v1; v = v5; v1 = c3*u - s3*v; v5 = s3*u + c3*v;
          u = v2; v = v6; v2 = c3*u - s3*v; v6 = s3*u + c3*v;
          u = v3; v = v7; v3 = c3*u - s3*v; v7 = s3*u + c3*v; }
        // layer-1 RY wire1: pairs (0,2),(1,3),(4,6),(5,7)
        { float u, v;
          u = v0; v = v2; v0 = c4*u - s4*v; v2 = s4*u + c4*v;
          u = v1; v = v3; v1 = c4*u - s4*v; v3 = s4*u + c4*v;
          u = v4; v = v6; v4 = c4*u - s4*v; v6 = s4*u + c4*v;
          u = v5; v = v7; v5 = c4*u - s4*v; v7 = s4*u + c4*v; }
        // layer-1 RY wire2: pairs (2k, 2k+1)
        { float u, v;
          u = v0; v = v1; v0 = c5*u - s5*v; v1 = s5*u + c5*v;
          u = v2; v = v3; v2 = c5*u - s5*v; v3 = s5*u + c5*v;
          u = v4; v = v5; v4 = c5*u - s5*v; v5 = s5*u + c5*v;
          u = v6; v = v7; v6 = c5*u - s5*v; v7 = s5*u + c5*v; }

        // layer-1 CNOT(0,1),CNOT(1,2) folded into measurement:
        // p[i] = f[i]^2 with f = [v0,v1,v3,v2,v6,v7,v5,v4]
        float q0 = v0*v0, q1 = v1*v1, q2 = v2*v2, q3 = v3*v3;
        float q4 = v4*v4, q5 = v5*v5, q6 = v6*v6, q7 = v7*v7;
        // <Z0>: +{p0..p3}={q0,q1,q3,q2}  -{p4..p7}={q6,q7,q5,q4}
        float o0 = (q0 + q1 + q2 + q3) - (q4 + q5 + q6 + q7);
        // <Z1>: +{p0,p1,p4,p5}={q0,q1,q6,q7}  -{p2,p3,p6,p7}={q3,q2,q5,q4}
        float o1 = (q0 + q1 + q6 + q7) - (q2 + q3 + q4 + q5);
        // <Z2>: +{p0,p2,p4,p6}={q0,q3,q6,q5}  -{p1,p3,p5,p7}={q1,q2,q7,q4}
        float o2 = (q0 + q3 + q5 + q6) - (q1 + q2 + q4 + q7);

        // stride-3 LDS writes: 3 coprime with 32 banks -> conflict-free
        sout[half * 768 + 3 * tid + 0] = o0;
        sout[half * 768 + 3 * tid + 1] = o1;
        sout[half * 768 + 3 * tid + 2] = o2;
    }
    __syncthreads();

    // 1536 contiguous output floats per block -> 768 float2, 3 per thread,
    // fully coalesced stride-1. (stride-8B LDS reads: 2-way alias = free)
    const long long T  = (long long)n * 3;
    const long long t2 = T >> 1;
    const long long b2 = (long long)blockIdx.x * 768;
    const float2* s2 = (const float2*)sout;
    float2* og = (float2*)out;
    #pragma unroll
    for (int k = 0; k < 3; ++k) {
        long long idx = b2 + k * 256 + tid;
        if (idx < t2) og[idx] = s2[k * 256 + tid];
    }
    // odd-total tail (impossible for even n; kept for safety)
    if ((T & 1) && tid == 0 && blockIdx.x == gridDim.x - 1) {
        out[T - 1] = sout[T - 1 - (long long)blockIdx.x * 1536];
    }
}

extern "C" void kernel_launch(void* const* d_in, const int* in_sizes, int n_in,
                              void* d_out, int out_size, void* d_ws, size_t ws_size,
                              hipStream_t stream) {
    const float4* x = (const float4*)d_in[0];   // (B, 4) float32, row = one float4
    const float*  w = (const float*)d_in[1];    // (2, 3) float32
    float* out = (float*)d_out;                 // (B, 3) float32
    int n = in_sizes[0] / 4;
    int blocks = (n + 511) / 512;
    qfl_kernel<<<blocks, 256, 0, stream>>>(x, w, out, n);
}